// Round 1
// baseline (1215.340 us; speedup 1.0000x reference)
//
#include <hip/hip_runtime.h>
#include <hip/hip_bf16.h>

#define H 128
#define BM 128      // rows per block
#define WROWS 32    // rows per wave

typedef __bf16 v8bf __attribute__((ext_vector_type(8)));
typedef float  v4f  __attribute__((ext_vector_type(4)));

__device__ __forceinline__ float silu_f(float z) {
    return z / (1.f + __expf(-z));
}

// Transpose + convert both W1 matrices (128x128 fp32, row-major [k][h])
// into bf16 W1T[h][k] in workspace.
__global__ void prep_w1(const float* __restrict__ pw1, const float* __restrict__ vw1,
                        __bf16* __restrict__ posT, __bf16* __restrict__ velT) {
    int id = blockIdx.x * 256 + threadIdx.x;   // 0..32767
    const float* src = (id < H * H) ? pw1 : vw1;
    __bf16*      dst = (id < H * H) ? posT : velT;
    int i = id & (H * H - 1);
    int h = i >> 7, k = i & 127;
    dst[i] = (__bf16)src[k * H + h];
}

// Fused  silu(A @ W1 + b1) @ w2 + b2  -> per-row scalar, then:
//   EDGE:  weight = (loc[send]-loc[rec]) * scalar; atomicAdd into out[rec]
//   NODE:  out[n] = loc[n] + scalar * vel[n]
template <bool EDGE>
__launch_bounds__(256, 3)
__global__ void mlp_kernel(const float* __restrict__ A,     // [rows,H]
                           const __bf16* __restrict__ w1t,  // [H,H] bf16, transposed
                           const float* __restrict__ b1,
                           const float* __restrict__ w2,
                           const float* __restrict__ b2,
                           const float* __restrict__ loc,
                           const float* __restrict__ vel,
                           const int* __restrict__ send,
                           const int* __restrict__ rec,
                           float* __restrict__ out,
                           int rows) {
    __shared__ __bf16 sW[H * 136];   // row stride 136 bf16 (pad kills bank conflicts)

    const int t = threadIdx.x;
    // Stage W1T (32 KB) into LDS: 2048 chunks of 16B, 256 threads x 8 iters.
#pragma unroll
    for (int it = 0; it < 8; ++it) {
        int c  = it * 256 + t;        // chunk index
        int r  = c >> 4;              // row (16 chunks of 8 bf16 per 128-row)
        int k0 = (c & 15) << 3;
        uint4 v = ((const uint4*)w1t)[c];
        *((uint4*)&sW[r * 136 + k0]) = v;
    }
    __syncthreads();

    const int lane = t & 63;
    const int wave = t >> 6;
    const int quad = lane >> 4;
    const int col  = lane & 15;
    const long rowBase = (long)blockIdx.x * BM + wave * WROWS;

    v4f zero4 = {0.f, 0.f, 0.f, 0.f};
    v4f acc[2][8];
#pragma unroll
    for (int rt = 0; rt < 2; ++rt)
#pragma unroll
        for (int i = 0; i < 8; ++i) acc[rt][i] = zero4;

#pragma unroll
    for (int s = 0; s < 4; ++s) {
        const int k0 = s * 32 + quad * 8;
        v8bf afr[2];
#pragma unroll
        for (int rt = 0; rt < 2; ++rt) {
            long row = rowBase + rt * 16 + col;
            v4f f0 = zero4, f1 = zero4;
            bool ok = EDGE || (row < (long)rows);
            if (ok) {
                const float* p = A + (size_t)row * H + k0;
                f0 = *((const v4f*)p);
                f1 = *((const v4f*)(p + 4));
            }
            v8bf a;
            a[0] = (__bf16)f0[0]; a[1] = (__bf16)f0[1];
            a[2] = (__bf16)f0[2]; a[3] = (__bf16)f0[3];
            a[4] = (__bf16)f1[0]; a[5] = (__bf16)f1[1];
            a[6] = (__bf16)f1[2]; a[7] = (__bf16)f1[3];
            afr[rt] = a;
        }
#pragma unroll
        for (int tt = 0; tt < 8; ++tt) {
            v8bf b = *((const v8bf*)&sW[(tt * 16 + col) * 136 + k0]);
            acc[0][tt] = __builtin_amdgcn_mfma_f32_16x16x32_bf16(afr[0], b, acc[0][tt], 0, 0, 0);
            acc[1][tt] = __builtin_amdgcn_mfma_f32_16x16x32_bf16(afr[1], b, acc[1][tt], 0, 0, 0);
        }
    }

    // Epilogue: bias + silu + dot(w2). Lane holds rows (rt*16 + quad*4 + i), col (tt*16 + col).
    float part[2][4] = {{0.f, 0.f, 0.f, 0.f}, {0.f, 0.f, 0.f, 0.f}};
#pragma unroll
    for (int tt = 0; tt < 8; ++tt) {
        float bias = b1[tt * 16 + col];
        float wv   = w2[tt * 16 + col];
#pragma unroll
        for (int rt = 0; rt < 2; ++rt)
#pragma unroll
            for (int i = 0; i < 4; ++i) {
                float z = acc[rt][tt][i] + bias;
                part[rt][i] += silu_f(z) * wv;
            }
    }
    // Reduce across the 16 lanes of each quad (cols).
#pragma unroll
    for (int m = 1; m < 16; m <<= 1)
#pragma unroll
        for (int rt = 0; rt < 2; ++rt)
#pragma unroll
            for (int i = 0; i < 4; ++i)
                part[rt][i] += __shfl_xor(part[rt][i], m, 64);

    // Distribute: lane r (<32) gets the scalar for row rowBase + r.
    int srcl = (lane & 12) << 2;   // quad holding row (r&15): ((r&15)>>2)*16
    float g0 = __shfl(part[0][0], srcl, 64);
    float g1 = __shfl(part[0][1], srcl, 64);
    float g2 = __shfl(part[0][2], srcl, 64);
    float g3 = __shfl(part[0][3], srcl, 64);
    float g4 = __shfl(part[1][0], srcl, 64);
    float g5 = __shfl(part[1][1], srcl, 64);
    float g6 = __shfl(part[1][2], srcl, 64);
    float g7 = __shfl(part[1][3], srcl, 64);
    float pmA = (lane & 2) ? ((lane & 1) ? g3 : g2) : ((lane & 1) ? g1 : g0);
    float pmB = (lane & 2) ? ((lane & 1) ? g7 : g6) : ((lane & 1) ? g5 : g4);
    float pm  = (lane & 16) ? pmB : pmA;
    float b2v = b2[0];

    if constexpr (EDGE) {
        if (lane < 32) {
            long e = rowBase + lane;
            float pmf = pm + b2v;
            int sd = send[e], rc = rec[e];
            float wx = (loc[sd * 3 + 0] - loc[rc * 3 + 0]) * pmf;
            float wy = (loc[sd * 3 + 1] - loc[rc * 3 + 1]) * pmf;
            float wz = (loc[sd * 3 + 2] - loc[rc * 3 + 2]) * pmf;
            atomicAdd(&out[rc * 3 + 0], wx);
            atomicAdd(&out[rc * 3 + 1], wy);
            atomicAdd(&out[rc * 3 + 2], wz);
        }
    } else {
        if (lane < 32) {
            long n = rowBase + lane;
            if (n < (long)rows) {
                float vm = pm + b2v;
                out[n * 3 + 0] = loc[n * 3 + 0] + vm * vel[n * 3 + 0];
                out[n * 3 + 1] = loc[n * 3 + 1] + vm * vel[n * 3 + 1];
                out[n * 3 + 2] = loc[n * 3 + 2] + vm * vel[n * 3 + 2];
            }
        }
    }
}

extern "C" void kernel_launch(void* const* d_in, const int* in_sizes, int n_in,
                              void* d_out, int out_size, void* d_ws, size_t ws_size,
                              hipStream_t stream) {
    const float* x    = (const float*)d_in[0];
    const float* vel  = (const float*)d_in[1];
    const float* loc  = (const float*)d_in[2];
    const float* mes  = (const float*)d_in[3];
    const int*   send = (const int*)d_in[4];
    const int*   rec  = (const int*)d_in[5];
    const float* pw1  = (const float*)d_in[6];
    const float* pb1  = (const float*)d_in[7];
    const float* pw2  = (const float*)d_in[8];
    const float* pb2  = (const float*)d_in[9];
    const float* vw1  = (const float*)d_in[10];
    const float* vb1  = (const float*)d_in[11];
    const float* vw2  = (const float*)d_in[12];
    const float* vb2  = (const float*)d_in[13];
    float* out = (float*)d_out;

    const int N = in_sizes[1] / 3;
    const int E = in_sizes[4];

    __bf16* posT = (__bf16*)d_ws;
    __bf16* velT = (__bf16*)((char*)d_ws + (size_t)H * H * sizeof(__bf16));

    // 1) transpose+convert weights (tiny)
    prep_w1<<<128, 256, 0, stream>>>(pw1, vw1, posT, velT);
    // 2) node MLP writes out = loc + vel_message*vel
    mlp_kernel<false><<<(N + BM - 1) / BM, 256, 0, stream>>>(
        x, velT, vb1, vw2, vb2, loc, vel, nullptr, nullptr, out, N);
    // 3) edge MLP atomically accumulates agg_mes into out
    mlp_kernel<true><<<E / BM, 256, 0, stream>>>(
        mes, posT, pb1, pw2, pb2, loc, nullptr, send, rec, out, E);
}